// Round 3
// baseline (556.363 us; speedup 1.0000x reference)
//
#include <hip/hip_runtime.h>
#include <hip/hip_bf16.h>

// GNN processor: NL=256, NP=8192, NV=16, B=2.
// R1: factored first edge layer (S/P/E gather trick) + fused MFMA MLPs. 555us.
// R2: 512-thread/MT=2 blocks (43% occ), merged launches. 481us.
// R3: E-GEMM inlined into edge_mlp (64-row blocks, E computed once). 471us.
// R4/R5: 128-row blocks -> REFUTED weight-L2 theory (236us edge, worse).
// R6: latency/TLP attack. Counters showed all pipes ~21% at 43% occ and
//     ~234us spent in tiny-grid producer/node/pack (1 block/CU, single-shot).
//     - edge: 256-thread/32-row blocks (1 pt x 16v x 2b), 17.9KB LDS,
//       launch_bounds(256,6) -> ~6 blocks/CU resident (was 2).
//     - producer/node: 1024 blocks x 16 rows x 256 thr (4-8 blocks/CU).
//     - pack_all: fragment-direct coalesced reads (88 blocks).

typedef __bf16 bf16;
typedef __bf16 bf16x8 __attribute__((ext_vector_type(8)));
typedef float f32x4 __attribute__((ext_vector_type(4)));

#define MFMA16(a, b, c) __builtin_amdgcn_mfma_f32_16x16x32_bf16((a), (b), (c), 0, 0, 0)

constexpr int kNP = 8192;
constexpr int kNV = 16;

// ---------------- weight packing (88 blocks, coalesced 64B reads) -----------
// fp32 W[K][N] -> bf16 fragment-ready:
// dst[((nt*kd + ks)*64 + lane)*8 + j] = W[ks*32 + (lane>>4)*8 + j][nt*16 + (lane&15)]
// Block = one (matrix, ks) slab. Each quarter-wave reads 16 consecutive n
// (64B line fully consumed); writes are 1KB contiguous per (nt,wave).
__global__ __launch_bounds__(256) void pack_all(
    const float* __restrict__ e_fw, const float* __restrict__ e_hw,
    const float* __restrict__ e_lw, const float* __restrict__ n_fw,
    const float* __restrict__ n_hw, const float* __restrict__ n_lw,
    bf16* __restrict__ wp) {
  const int s = blockIdx.x;  // 0..87
  const float* src;
  bf16* dst;
  int ks, kd = 8;
  if (s < 24)      { src = e_fw + (s >> 3) * 65536; dst = wp + (s >> 3) * 65536; ks = s & 7; }
  else if (s < 32) { src = e_hw;          dst = wp + 196608; ks = s - 24; }
  else if (s < 40) { src = e_hw + 65536;  dst = wp + 262144; ks = s - 32; }
  else if (s < 48) { src = e_lw;          dst = wp + 327680; ks = s - 40; }
  else if (s < 64) { src = n_fw;          dst = wp + 393216; ks = s - 48; kd = 16; }
  else if (s < 72) { src = n_hw;          dst = wp + 524288; ks = s - 64; }
  else if (s < 80) { src = n_hw + 65536;  dst = wp + 589824; ks = s - 72; }
  else             { src = n_lw;          dst = wp + 655360; ks = s - 80; }
  const int t = threadIdx.x;
  const int lane = t & 63;
  const int w = t >> 6;
  const int q = lane >> 4;
  const int c = lane & 15;
#pragma unroll
  for (int nti = 0; nti < 4; nti++) {
    const int nt = w * 4 + nti;
    bf16x8 v;
#pragma unroll
    for (int j = 0; j < 8; j++)
      v[j] = (bf16)src[(ks * 32 + q * 8 + j) * 256 + nt * 16 + c];
    *(bf16x8*)(dst + (((nt * kd + ks) * 64 + lane) << 3)) = v;
  }
}

// ---------------- MFMA layer primitives ----------------
// Block = 4 waves (256 thr): wave w = col-group wc (64 cols each), MT row tiles.
// X: LDS [rows][280] bf16 (K+24 pad). A-frag from LDS, B-frag lane-ordered
// packed global load (1KB coalesced, L2-hot).
// C/D: col = lane&15, row = (lane>>4)*4 + i
template <int KD, int MT>
__device__ __forceinline__ void layer_acc(const bf16* X, int xs,
                                          const bf16* __restrict__ Wp,
                                          const float* __restrict__ bias,
                                          f32x4 (&acc)[MT][4], int rowOff,
                                          int wc) {
  const int lane = threadIdx.x & 63;
  const int q = lane >> 4;
  const int c = lane & 15;
#pragma unroll
  for (int nt = 0; nt < 4; nt++) {
    float bv = bias ? bias[wc * 64 + nt * 16 + c] : 0.0f;
#pragma unroll
    for (int mt = 0; mt < MT; mt++) {
      acc[mt][nt][0] = bv; acc[mt][nt][1] = bv;
      acc[mt][nt][2] = bv; acc[mt][nt][3] = bv;
    }
  }
#pragma unroll
  for (int ks = 0; ks < KD; ks++) {
    bf16x8 a[MT];
#pragma unroll
    for (int mt = 0; mt < MT; mt++)
      a[mt] = *(const bf16x8*)(X + (rowOff + mt * 16 + c) * xs + ks * 32 + q * 8);
    bf16x8 bb[4];
#pragma unroll
    for (int nt = 0; nt < 4; nt++)
      bb[nt] = *(const bf16x8*)(Wp + ((((wc * 4 + nt) * KD + ks) * 64 + lane) << 3));
#pragma unroll
    for (int mt = 0; mt < MT; mt++)
#pragma unroll
      for (int nt = 0; nt < 4; nt++)
        acc[mt][nt] = MFMA16(a[mt], bb[nt], acc[mt][nt]);
  }
}

template <int KD, int MT, bool RELU>
__device__ __forceinline__ void layer_inplace(bf16* X, int xs_r, int xs_w,
                                              const bf16* __restrict__ Wp,
                                              const float* __restrict__ bias,
                                              int rowOff, int wc) {
  f32x4 acc[MT][4];
  layer_acc<KD, MT>(X, xs_r, Wp, bias, acc, rowOff, wc);
  const int lane = threadIdx.x & 63;
  const int q = lane >> 4;
  const int c = lane & 15;
  __syncthreads();  // all waves done reading X before overwrite
#pragma unroll
  for (int mt = 0; mt < MT; mt++)
#pragma unroll
    for (int nt = 0; nt < 4; nt++)
#pragma unroll
      for (int i = 0; i < 4; i++) {
        float v = acc[mt][nt][i];
        if (RELU) v = fmaxf(v, 0.0f);
        X[(rowOff + mt * 16 + q * 4 + i) * xs_w + (wc * 64 + nt * 16 + c)] = (bf16)v;
      }
  __syncthreads();
}

// ---------------- S+P producer: one staged tile, two GEMMs ----------------
// 1024 blocks x 16 rows x 256 thr: S = nodes@Wa + e_fb ; P = nodes@Wb.
__global__ __launch_bounds__(256, 8) void producer_sp(
    const float* __restrict__ nodes, const bf16* __restrict__ w_self,
    const bf16* __restrict__ w_nb, const float* __restrict__ e_fb,
    bf16* __restrict__ Sb, bf16* __restrict__ Pb) {
  __shared__ bf16 X[16 * 280];
  const int t = threadIdx.x;
  const int m0 = blockIdx.x * 16;
  {
    const int r = t >> 4;     // 16 rows, 16 threads/row
    const int q16 = t & 15;   // 16 floats (64B) each
    const float* src = nodes + (m0 + r) * 256 + q16 * 16;
    bf16* dst = X + r * 280 + q16 * 16;
    float4 f0 = *(const float4*)(src);
    float4 f1 = *(const float4*)(src + 4);
    float4 f2 = *(const float4*)(src + 8);
    float4 f3 = *(const float4*)(src + 12);
    bf16x8 v0, v1;
    v0[0] = (bf16)f0.x; v0[1] = (bf16)f0.y; v0[2] = (bf16)f0.z; v0[3] = (bf16)f0.w;
    v0[4] = (bf16)f1.x; v0[5] = (bf16)f1.y; v0[6] = (bf16)f1.z; v0[7] = (bf16)f1.w;
    v1[0] = (bf16)f2.x; v1[1] = (bf16)f2.y; v1[2] = (bf16)f2.z; v1[3] = (bf16)f2.w;
    v1[4] = (bf16)f3.x; v1[5] = (bf16)f3.y; v1[6] = (bf16)f3.z; v1[7] = (bf16)f3.w;
    *(bf16x8*)(dst) = v0;
    *(bf16x8*)(dst + 8) = v1;
  }
  __syncthreads();
  const int lane = t & 63;
  const int wc = t >> 6;  // 4 waves = 4 col-groups
  const int q = lane >> 4;
  const int c = lane & 15;
  f32x4 acc[1][4];
  layer_acc<8, 1>(X, 280, w_self, e_fb, acc, 0, wc);
#pragma unroll
  for (int nt = 0; nt < 4; nt++)
#pragma unroll
    for (int i = 0; i < 4; i++)
      Sb[(m0 + q * 4 + i) * 256 + wc * 64 + nt * 16 + c] = (bf16)acc[0][nt][i];
  layer_acc<8, 1>(X, 280, w_nb, nullptr, acc, 0, wc);
#pragma unroll
  for (int nt = 0; nt < 4; nt++)
#pragma unroll
    for (int i = 0; i < 4; i++)
      Pb[(m0 + q * 4 + i) * 256 + wc * 64 + nt * 16 + c] = (bf16)acc[0][nt][i];
}

// ---------------- fused edge MLP: inline E + layers 2..4 + aggregation ------
// Block = 1 point x 16 v x 2 batches = 32 rows, 256 threads (4 waves, wc split,
// MT=2). E (16 rows) computed once in rows 16..31, shared by both batches.
// X rows 0-15 = b0 edges, 16-31 = b1 edges after assembly.
__global__ __launch_bounds__(256, 6) void edge_mlp(
    const bf16* __restrict__ S, const bf16* __restrict__ P,
    const float* __restrict__ eattr, const int* __restrict__ idx,
    const bf16* __restrict__ w_ea, const bf16* __restrict__ Wh0,
    const bf16* __restrict__ Wh1, const bf16* __restrict__ Wl,
    const float* __restrict__ e_hb, const float* __restrict__ e_lb,
    bf16* __restrict__ agg, float* __restrict__ out_edges) {
  __shared__ bf16 X[32 * 280];
  const int t = threadIdx.x;
  const int p = blockIdx.x;  // 8192 blocks, one point each
  // ---- stage eattr (16 rows fp32) into X rows 16..31 as bf16
  {
    const int r = t >> 4;     // 0..15, 16 threads/row
    const int q16 = t & 15;   // 16 floats (64B) each
    const float* src = eattr + (p * 16 + r) * 256 + q16 * 16;
    bf16* dst = X + (16 + r) * 280 + q16 * 16;
    float4 f0 = *(const float4*)(src);
    float4 f1 = *(const float4*)(src + 4);
    float4 f2 = *(const float4*)(src + 8);
    float4 f3 = *(const float4*)(src + 12);
    bf16x8 v0, v1;
    v0[0] = (bf16)f0.x; v0[1] = (bf16)f0.y; v0[2] = (bf16)f0.z; v0[3] = (bf16)f0.w;
    v0[4] = (bf16)f1.x; v0[5] = (bf16)f1.y; v0[6] = (bf16)f1.z; v0[7] = (bf16)f1.w;
    v1[0] = (bf16)f2.x; v1[1] = (bf16)f2.y; v1[2] = (bf16)f2.z; v1[3] = (bf16)f2.w;
    v1[4] = (bf16)f3.x; v1[5] = (bf16)f3.y; v1[6] = (bf16)f3.z; v1[7] = (bf16)f3.w;
    *(bf16x8*)(dst) = v0;
    *(bf16x8*)(dst + 8) = v1;
  }
  __syncthreads();
  const int lane = t & 63;
  const int wc = t >> 6;  // 4 waves = 4 col-groups
  const int q = lane >> 4;
  const int c = lane & 15;
  // ---- inline E-GEMM over the 16 staged rows (E = eattr @ Wc, no bias)
  {
    f32x4 acce[1][4];
    layer_acc<8, 1>(X, 280, w_ea, nullptr, acce, 16, wc);
    __syncthreads();  // all A-frag reads done before in-place E write
#pragma unroll
    for (int nt = 0; nt < 4; nt++)
#pragma unroll
      for (int i = 0; i < 4; i++)
        X[(16 + q * 4 + i) * 280 + wc * 64 + nt * 16 + c] = (bf16)acce[0][nt][i];
  }
  __syncthreads();
  // ---- assemble relu(S + Pgather + E) for both batches (rows 0..31)
  {
    const int r = t >> 3;     // 0..31, 8 threads/row
    const int q8 = t & 7;     // 32 cols each
    const int b = r >> 4;
    const int v = r & 15;
    const int nb = idx[p * kNV + v];
    const bf16* Srow = S + ((b << 13) + p) * 256;
    const bf16* Prow = P + ((b << 13) + nb) * 256;
    bf16x8 hold[4];
#pragma unroll
    for (int j = 0; j < 4; j++) {
      int col = q8 * 32 + j * 8;
      bf16x8 ev = *(const bf16x8*)(X + (16 + v) * 280 + col);
      bf16x8 sv = *(const bf16x8*)(Srow + col);
      bf16x8 pv = *(const bf16x8*)(Prow + col);
      bf16x8 o;
#pragma unroll
      for (int k = 0; k < 8; k++) {
        float f = (float)sv[k] + (float)pv[k] + (float)ev[k];
        o[k] = (bf16)fmaxf(f, 0.0f);
      }
      hold[j] = o;
    }
    __syncthreads();  // E reads done everywhere before rows are overwritten
#pragma unroll
    for (int j = 0; j < 4; j++)
      *(bf16x8*)(X + r * 280 + q8 * 32 + j * 8) = hold[j];
  }
  __syncthreads();
  // ---- hidden layers + last layer (MT=2: wave covers all 32 rows)
  layer_inplace<8, 2, true>(X, 280, 280, Wh0, e_hb, 0, wc);
  layer_inplace<8, 2, true>(X, 280, 280, Wh1, e_hb + 256, 0, wc);
  f32x4 acc[2][4];
  layer_acc<8, 2>(X, 280, Wl, e_lb, acc, 0, wc);
  // ---- NV-aggregation: tile mt -> batch mt, point p (sum over 16 rows = v)
#pragma unroll
  for (int mt = 0; mt < 2; mt++) {
#pragma unroll
    for (int nt = 0; nt < 4; nt++) {
      float s = acc[mt][nt][0] + acc[mt][nt][1] + acc[mt][nt][2] + acc[mt][nt][3];
      s += __shfl_xor(s, 16, 64);
      s += __shfl_xor(s, 32, 64);
      if (lane < 16)
        agg[((mt << 13) + p) * 256 + wc * 64 + nt * 16 + lane] = (bf16)s;
    }
  }
  // ---- batch-0 edge outputs (tile mt=0, rows 0..15 = v)
#pragma unroll
  for (int nt = 0; nt < 4; nt++)
#pragma unroll
    for (int i = 0; i < 4; i++) {
      int e = p * kNV + q * 4 + i;
      out_edges[e * 256 + wc * 64 + nt * 16 + c] = acc[0][nt][i];
    }
}

// ---------------- fused node MLP + residual ----------------
// 1024 blocks x 16 rows x 256 thr (4 waves, wc split, MT=1).
__global__ __launch_bounds__(256, 8) void node_mlp(
    const float* __restrict__ nodes, const bf16* __restrict__ agg,
    const bf16* __restrict__ Wf, const bf16* __restrict__ Wh0,
    const bf16* __restrict__ Wh1, const bf16* __restrict__ Wl,
    const float* __restrict__ n_fb, const float* __restrict__ n_hb,
    const float* __restrict__ n_lb, float* __restrict__ out_nodes) {
  __shared__ bf16 X[16 * 536];
  const int t = threadIdx.x;
  const int r = t >> 4;     // 16 rows, 16 threads/row
  const int q16 = t & 15;   // 32 cols each; <8 -> nodes, >=8 -> agg
  const int m = blockIdx.x * 16 + r;
  if (q16 < 8) {
    const float* src = nodes + m * 256 + q16 * 32;
    bf16* dst = X + r * 536 + q16 * 32;
#pragma unroll
    for (int h = 0; h < 4; h++) {
      float4 f0 = *(const float4*)(src + h * 8);
      float4 f1 = *(const float4*)(src + h * 8 + 4);
      bf16x8 v;
      v[0] = (bf16)f0.x; v[1] = (bf16)f0.y; v[2] = (bf16)f0.z; v[3] = (bf16)f0.w;
      v[4] = (bf16)f1.x; v[5] = (bf16)f1.y; v[6] = (bf16)f1.z; v[7] = (bf16)f1.w;
      *(bf16x8*)(dst + h * 8) = v;
    }
  } else {
    const bf16* src = agg + m * 256 + (q16 - 8) * 32;
    bf16* dst = X + r * 536 + 256 + (q16 - 8) * 32;
#pragma unroll
    for (int h = 0; h < 4; h++)
      *(bf16x8*)(dst + h * 8) = *(const bf16x8*)(src + h * 8);
  }
  __syncthreads();
  const int wc = t >> 6;
  layer_inplace<16, 1, true>(X, 536, 280, Wf, n_fb, 0, wc);
  layer_inplace<8, 1, true>(X, 280, 280, Wh0, n_hb, 0, wc);
  layer_inplace<8, 1, true>(X, 280, 280, Wh1, n_hb + 256, 0, wc);
  f32x4 acc[1][4];
  layer_acc<8, 1>(X, 280, Wl, n_lb, acc, 0, wc);
  const int lane = t & 63;
  const int q = lane >> 4;
  const int c = lane & 15;
#pragma unroll
  for (int nt = 0; nt < 4; nt++)
#pragma unroll
    for (int i = 0; i < 4; i++) {
      int mm = blockIdx.x * 16 + q * 4 + i;
      int col = wc * 64 + nt * 16 + c;
      out_nodes[mm * 256 + col] = nodes[mm * 256 + col] + acc[0][nt][i];
    }
}

// ---------------- launch ----------------
extern "C" void kernel_launch(void* const* d_in, const int* in_sizes, int n_in,
                              void* d_out, int out_size, void* d_ws,
                              size_t ws_size, hipStream_t stream) {
  const float* nodes = (const float*)d_in[0];
  const float* eattr = (const float*)d_in[1];
  const int* eidx = (const int*)d_in[2];
  const float* e_fw = (const float*)d_in[3];
  const float* e_fb = (const float*)d_in[4];
  const float* e_hw = (const float*)d_in[5];
  const float* e_hb = (const float*)d_in[6];
  const float* e_lw = (const float*)d_in[7];
  const float* e_lb = (const float*)d_in[8];
  const float* n_fw = (const float*)d_in[9];
  const float* n_fb = (const float*)d_in[10];
  const float* n_hw = (const float*)d_in[11];
  const float* n_hb = (const float*)d_in[12];
  const float* n_lw = (const float*)d_in[13];
  const float* n_lb = (const float*)d_in[14];

  // workspace map (bytes); total ~26.6 MB
  char* ws = (char*)d_ws;
  bf16* Sb = (bf16*)(ws + 0);            // [16384][256]
  bf16* Pb = (bf16*)(ws + 8388608);      // [16384][256]
  bf16* aggb = (bf16*)(ws + 16777216);   // [16384][256]
  bf16* wp = (bf16*)(ws + 25165824);     // packed-weight arena, 720896 elems
  bf16* w_self = wp;
  bf16* w_nb = wp + 65536;
  bf16* w_ea = wp + 131072;
  bf16* w_eh0 = wp + 196608;
  bf16* w_eh1 = wp + 262144;
  bf16* w_el = wp + 327680;
  bf16* w_nf = wp + 393216;              // 131072 elems (K=512)
  bf16* w_nh0 = wp + 524288;
  bf16* w_nh1 = wp + 589824;
  bf16* w_nl = wp + 655360;

  float* out_nodes = (float*)d_out;
  float* out_edges = (float*)d_out + 4194304;  // after [B,NP,NL] nodes

  pack_all<<<88, 256, 0, stream>>>(e_fw, e_hw, e_lw, n_fw, n_hw, n_lw, wp);
  producer_sp<<<1024, 256, 0, stream>>>(nodes, w_self, w_nb, e_fb, Sb, Pb);
  edge_mlp<<<8192, 256, 0, stream>>>(Sb, Pb, eattr, eidx, w_ea, w_eh0, w_eh1,
                                     w_el, e_hb, e_lb, aggb, out_edges);
  node_mlp<<<1024, 256, 0, stream>>>(nodes, aggb, w_nf, w_nh0, w_nh1, w_nl,
                                     n_fb, n_hb, n_lb, out_nodes);
}

// Round 4
// 470.768 us; speedup vs baseline: 1.1818x; 1.1818x over previous
//
#include <hip/hip_runtime.h>
#include <hip/hip_bf16.h>

// GNN processor: NL=256, NP=8192, NV=16, B=2.
// R1: factored first edge layer (S/P/E gather trick) + fused MFMA MLPs. 555us.
// R2: 512-thread/MT=2 blocks (43% occ), merged launches. 481us.
// R3: E-GEMM inlined into edge_mlp (64-row blocks, E computed once). 471us.
// R4/R5: 128-row blocks -> REFUTED weight-L2-BW theory (236us edge, worse).
// R6: 32-row/256-thr blocks, 64% occ -> REFUTED occupancy theory (287us edge,
//     HBM write amplification 308MB). R3 shape = measured optimum.
// R7: issue-port theory: per-SIMD instruction issue is ~2.5x oversubscribed
//     (5 waves x ~1000cy demand per ~2000cy layer wall) -> MFMA pipe capped
//     ~25% regardless of occupancy/traffic. Fix: edge hidden/last layers use
//     mfma_32x32x16 (32 MFMA/wave/layer vs 64, -20% pipe cycles; same load
//     and epilogue instr counts). out_edges stores become full 128B lines.
//     producer/node/E/assembly restored to R3-exact.

typedef __bf16 bf16;
typedef __bf16 bf16x8 __attribute__((ext_vector_type(8)));
typedef float f32x4 __attribute__((ext_vector_type(4)));
typedef float f32x16 __attribute__((ext_vector_type(16)));

#define MFMA16(a, b, c) __builtin_amdgcn_mfma_f32_16x16x32_bf16((a), (b), (c), 0, 0, 0)
#define MFMA32(a, b, c) __builtin_amdgcn_mfma_f32_32x32x16_bf16((a), (b), (c), 0, 0, 0)

constexpr int kNP = 8192;
constexpr int kNV = 16;

// ---------------- weight packing (112 blocks, coalesced reads) --------------
// 16x16 layout (producer/node/E): dst[((nt*kd+ks)*64+lane)*8+j]
//   = W[ks*32+(lane>>4)*8+j][nt*16+(lane&15)]
// 32x32 layout (edge hidden/last): dst[((wcnt*16+ks)*64+lane)*8+j]
//   = W[ks*16+(lane>>5)*8+j][wcnt*32+(lane&31)]
__global__ __launch_bounds__(256) void pack_all(
    const float* __restrict__ e_fw, const float* __restrict__ e_hw,
    const float* __restrict__ e_lw, const float* __restrict__ n_fw,
    const float* __restrict__ n_hw, const float* __restrict__ n_lw,
    bf16* __restrict__ wp) {
  const int s = blockIdx.x;  // 0..111
  const int t = threadIdx.x;
  const int lane = t & 63;
  const int w = t >> 6;
  if (s < 64) {  // ---- 16x16 fragment packing
    const float* src;
    bf16* dst;
    int ks, kd = 8;
    if (s < 24)      { src = e_fw + (s >> 3) * 65536; dst = wp + (s >> 3) * 65536; ks = s & 7; }
    else if (s < 40) { src = n_fw;          dst = wp + 393216; ks = s - 24; kd = 16; }
    else if (s < 48) { src = n_hw;          dst = wp + 524288; ks = s - 40; }
    else if (s < 56) { src = n_hw + 65536;  dst = wp + 589824; ks = s - 48; }
    else             { src = n_lw;          dst = wp + 655360; ks = s - 56; }
    const int q = lane >> 4;
    const int c = lane & 15;
#pragma unroll
    for (int nti = 0; nti < 4; nti++) {
      const int nt = w * 4 + nti;
      bf16x8 v;
#pragma unroll
      for (int j = 0; j < 8; j++)
        v[j] = (bf16)src[(ks * 32 + q * 8 + j) * 256 + nt * 16 + c];
      *(bf16x8*)(dst + (((nt * kd + ks) * 64 + lane) << 3)) = v;
    }
  } else {  // ---- 32x32 fragment packing: e_hw0 / e_hw1 / e_lw
    const int s2 = s - 64;
    const int mat = s2 >> 4;    // 0..2
    const int ks = s2 & 15;     // 0..15
    const float* src = (mat == 0) ? e_hw : (mat == 1) ? (e_hw + 65536) : e_lw;
    bf16* dst = wp + 196608 + mat * 65536;
    const int ko = lane >> 5;
    const int col = lane & 31;
#pragma unroll
    for (int h = 0; h < 2; h++) {
      const int wcnt = w * 2 + h;  // 0..7
      bf16x8 v;
#pragma unroll
      for (int j = 0; j < 8; j++)
        v[j] = (bf16)src[(ks * 16 + ko * 8 + j) * 256 + wcnt * 32 + col];
      *(bf16x8*)(dst + (((wcnt * 16 + ks) * 64 + lane) << 3));
      *(bf16x8*)(dst + (((wcnt * 16 + ks) * 64 + lane) << 3)) = v;
    }
  }
}

// ---------------- 16x16 MFMA layer primitives (producer/node/E) -------------
// C/D: col = lane&15, row = (lane>>4)*4 + i
template <int KD, int MT>
__device__ __forceinline__ void layer_acc(const bf16* X, int xs,
                                          const bf16* __restrict__ Wp,
                                          const float* __restrict__ bias,
                                          f32x4 (&acc)[MT][4], int rowOff,
                                          int wc) {
  const int lane = threadIdx.x & 63;
  const int q = lane >> 4;
  const int c = lane & 15;
#pragma unroll
  for (int nt = 0; nt < 4; nt++) {
    float bv = bias ? bias[wc * 64 + nt * 16 + c] : 0.0f;
#pragma unroll
    for (int mt = 0; mt < MT; mt++) {
      acc[mt][nt][0] = bv; acc[mt][nt][1] = bv;
      acc[mt][nt][2] = bv; acc[mt][nt][3] = bv;
    }
  }
#pragma unroll
  for (int ks = 0; ks < KD; ks++) {
    bf16x8 a[MT];
#pragma unroll
    for (int mt = 0; mt < MT; mt++)
      a[mt] = *(const bf16x8*)(X + (rowOff + mt * 16 + c) * xs + ks * 32 + q * 8);
    bf16x8 bb[4];
#pragma unroll
    for (int nt = 0; nt < 4; nt++)
      bb[nt] = *(const bf16x8*)(Wp + ((((wc * 4 + nt) * KD + ks) * 64 + lane) << 3));
#pragma unroll
    for (int mt = 0; mt < MT; mt++)
#pragma unroll
      for (int nt = 0; nt < 4; nt++)
        acc[mt][nt] = MFMA16(a[mt], bb[nt], acc[mt][nt]);
  }
}

template <int KD, int MT, bool RELU>
__device__ __forceinline__ void layer_inplace(bf16* X, int xs_r, int xs_w,
                                              const bf16* __restrict__ Wp,
                                              const float* __restrict__ bias,
                                              int rowOff, int wc) {
  f32x4 acc[MT][4];
  layer_acc<KD, MT>(X, xs_r, Wp, bias, acc, rowOff, wc);
  const int lane = threadIdx.x & 63;
  const int q = lane >> 4;
  const int c = lane & 15;
  __syncthreads();  // all waves done reading X before overwrite
#pragma unroll
  for (int mt = 0; mt < MT; mt++)
#pragma unroll
    for (int nt = 0; nt < 4; nt++)
#pragma unroll
      for (int i = 0; i < 4; i++) {
        float v = acc[mt][nt][i];
        if (RELU) v = fmaxf(v, 0.0f);
        X[(rowOff + mt * 16 + q * 4 + i) * xs_w + (wc * 64 + nt * 16 + c)] = (bf16)v;
      }
  __syncthreads();
}

// ---------------- 32x32 MFMA layer primitives (edge hidden/last) ------------
// Wave tile: 32 rows x 64 cols (2 nt' of 32 cols), K via KD2 steps of 16.
// A-frag: lane holds A[row=lane&31][k=ks*16+(lane>>5)*8+j]
// B-frag: lane holds W[k=ks*16+(lane>>5)*8+j][col=wcnt*32+(lane&31)]
// C/D: col = lane&31, row = (r&3) + 8*(r>>2) + 4*(lane>>5), r in [0,16)
template <int KD2>
__device__ __forceinline__ void layer_acc32(const bf16* X, int xs,
                                            const bf16* __restrict__ Wp,
                                            const float* __restrict__ bias,
                                            f32x16 (&acc)[2], int rowOff,
                                            int wc) {
  const int lane = threadIdx.x & 63;
  const int row = lane & 31;
  const int ko = lane >> 5;
  const int col = lane & 31;
#pragma unroll
  for (int nt = 0; nt < 2; nt++) {
    float bv = bias ? bias[wc * 64 + nt * 32 + col] : 0.0f;
#pragma unroll
    for (int r = 0; r < 16; r++) acc[nt][r] = bv;
  }
#pragma unroll
  for (int ks = 0; ks < KD2; ks++) {
    bf16x8 a = *(const bf16x8*)(X + (rowOff + row) * xs + ks * 16 + ko * 8);
#pragma unroll
    for (int nt = 0; nt < 2; nt++) {
      bf16x8 b = *(const bf16x8*)(Wp + ((((wc * 2 + nt) * KD2 + ks) * 64 + lane) << 3));
      acc[nt] = MFMA32(a, b, acc[nt]);
    }
  }
}

template <int KD2, bool RELU>
__device__ __forceinline__ void layer_inplace32(bf16* X, int xs,
                                                const bf16* __restrict__ Wp,
                                                const float* __restrict__ bias,
                                                int rowOff, int wc) {
  f32x16 acc[2];
  layer_acc32<KD2>(X, xs, Wp, bias, acc, rowOff, wc);
  const int lane = threadIdx.x & 63;
  const int h = lane >> 5;
  const int col = lane & 31;
  __syncthreads();  // all waves done reading X before overwrite
#pragma unroll
  for (int nt = 0; nt < 2; nt++)
#pragma unroll
    for (int r = 0; r < 16; r++) {
      float v = acc[nt][r];
      if (RELU) v = fmaxf(v, 0.0f);
      const int rr = (r & 3) + 8 * (r >> 2) + 4 * h;
      X[(rowOff + rr) * xs + (wc * 64 + nt * 32 + col)] = (bf16)v;
    }
  __syncthreads();
}

// ---------------- S+P producer: one staged tile, two GEMMs (R3-exact) -------
// 256 blocks x 64 rows: S = nodes@Wa + e_fb ; P = nodes@Wb. Direct acc->global.
__global__ __launch_bounds__(512, 4) void producer_sp(
    const float* __restrict__ nodes, const bf16* __restrict__ w_self,
    const bf16* __restrict__ w_nb, const float* __restrict__ e_fb,
    bf16* __restrict__ Sb, bf16* __restrict__ Pb) {
  __shared__ bf16 X[64 * 280];
  const int t = threadIdx.x;
  const int m0 = blockIdx.x * 64;
  {
    const int r = t >> 3;   // 64 rows, 8 threads/row
    const int q8 = t & 7;
#pragma unroll
    for (int c8 = 0; c8 < 4; c8++) {
      int col = q8 * 8 + c8 * 64;
      float4 f0 = *(const float4*)(nodes + (m0 + r) * 256 + col);
      float4 f1 = *(const float4*)(nodes + (m0 + r) * 256 + col + 4);
      bf16x8 v;
      v[0] = (bf16)f0.x; v[1] = (bf16)f0.y; v[2] = (bf16)f0.z; v[3] = (bf16)f0.w;
      v[4] = (bf16)f1.x; v[5] = (bf16)f1.y; v[6] = (bf16)f1.z; v[7] = (bf16)f1.w;
      *(bf16x8*)(X + r * 280 + col) = v;
    }
  }
  __syncthreads();
  const int lane = t & 63;
  const int w = t >> 6;
  const int wc = w & 3;
  const int rowOff = (w >> 2) * 32;
  const int q = lane >> 4;
  const int c = lane & 15;
  f32x4 acc[2][4];
  layer_acc<8, 2>(X, 280, w_self, e_fb, acc, rowOff, wc);
#pragma unroll
  for (int mt = 0; mt < 2; mt++)
#pragma unroll
    for (int nt = 0; nt < 4; nt++)
#pragma unroll
      for (int i = 0; i < 4; i++)
        Sb[(m0 + rowOff + mt * 16 + q * 4 + i) * 256 + wc * 64 + nt * 16 + c] =
            (bf16)acc[mt][nt][i];
  layer_acc<8, 2>(X, 280, w_nb, nullptr, acc, rowOff, wc);
#pragma unroll
  for (int mt = 0; mt < 2; mt++)
#pragma unroll
    for (int nt = 0; nt < 4; nt++)
#pragma unroll
      for (int i = 0; i < 4; i++)
        Pb[(m0 + rowOff + mt * 16 + q * 4 + i) * 256 + wc * 64 + nt * 16 + c] =
            (bf16)acc[mt][nt][i];
}

// ---------------- fused edge MLP: inline E + layers 2..4 + aggregation ------
// Block = 2 points x 16 v x 2 batches = 64 rows (R3 shape). E (32 rows)
// computed once via 16x16 path, shared by both batches. Hidden/last layers
// use 32x32 MFMA: wave rg covers its 32-row batch tile (rg = batch).
__global__ __launch_bounds__(512, 4) void edge_mlp(
    const bf16* __restrict__ S, const bf16* __restrict__ P,
    const float* __restrict__ eattr, const int* __restrict__ idx,
    const bf16* __restrict__ w_ea, const bf16* __restrict__ Wh0,
    const bf16* __restrict__ Wh1, const bf16* __restrict__ Wl,
    const float* __restrict__ e_hb, const float* __restrict__ e_lb,
    bf16* __restrict__ agg, float* __restrict__ out_edges) {
  __shared__ bf16 X[64 * 280];
  const int t = threadIdx.x;
  const int pbase = blockIdx.x * 2;  // 4096 blocks
  // ---- stage eattr (32 rows fp32) into X rows 32..63 as bf16
  {
    const int r = t >> 4;     // 0..31
    const int q16 = t & 15;   // 16 cols each
    const float* src = eattr + (pbase * 16 + r) * 256 + q16 * 16;
    bf16* dst = X + (32 + r) * 280 + q16 * 16;
    float4 f0 = *(const float4*)(src);
    float4 f1 = *(const float4*)(src + 4);
    float4 f2 = *(const float4*)(src + 8);
    float4 f3 = *(const float4*)(src + 12);
    bf16x8 v0, v1;
    v0[0] = (bf16)f0.x; v0[1] = (bf16)f0.y; v0[2] = (bf16)f0.z; v0[3] = (bf16)f0.w;
    v0[4] = (bf16)f1.x; v0[5] = (bf16)f1.y; v0[6] = (bf16)f1.z; v0[7] = (bf16)f1.w;
    v1[0] = (bf16)f2.x; v1[1] = (bf16)f2.y; v1[2] = (bf16)f2.z; v1[3] = (bf16)f2.w;
    v1[4] = (bf16)f3.x; v1[5] = (bf16)f3.y; v1[6] = (bf16)f3.z; v1[7] = (bf16)f3.w;
    *(bf16x8*)(dst) = v0;
    *(bf16x8*)(dst + 8) = v1;
  }
  __syncthreads();
  const int lane = t & 63;
  const int w = t >> 6;
  const int wc = w & 3;
  const int rg = w >> 2;
  const int q = lane >> 4;
  const int c = lane & 15;
  // ---- inline E-GEMM over the 32 staged rows (16x16 path, E = eattr @ Wc)
  {
    f32x4 acce[1][4];
    layer_acc<8, 1>(X, 280, w_ea, nullptr, acce, 32 + rg * 16, wc);
    __syncthreads();  // all A-frag reads done before in-place E write
#pragma unroll
    for (int nt = 0; nt < 4; nt++)
#pragma unroll
      for (int i = 0; i < 4; i++)
        X[(32 + rg * 16 + q * 4 + i) * 280 + wc * 64 + nt * 16 + c] =
            (bf16)acce[0][nt][i];
  }
  __syncthreads();
  // ---- assemble relu(S + Pgather + E) for both batches
  {
    const int r = t >> 3;     // 0..63
    const int q8 = t & 7;     // 32 cols each
    const int b = r >> 5;
    const int rr = r & 31;
    const int p = pbase + (rr >> 4);
    const int v = rr & 15;
    const int nb = idx[p * kNV + v];
    const bf16* Srow = S + ((b << 13) + p) * 256;
    const bf16* Prow = P + ((b << 13) + nb) * 256;
    bf16x8 hold[4];
#pragma unroll
    for (int j = 0; j < 4; j++) {
      int col = q8 * 32 + j * 8;
      bf16x8 ev = *(const bf16x8*)(X + (32 + rr) * 280 + col);
      bf16x8 sv = *(const bf16x8*)(Srow + col);
      bf16x8 pv = *(const bf16x8*)(Prow + col);
      bf16x8 o;
#pragma unroll
      for (int k = 0; k < 8; k++) {
        float f = (float)sv[k] + (float)pv[k] + (float)ev[k];
        o[k] = (bf16)fmaxf(f, 0.0f);
      }
      hold[j] = o;
    }
    __syncthreads();  // E reads done everywhere before rows are overwritten
#pragma unroll
    for (int j = 0; j < 4; j++)
      *(bf16x8*)(X + r * 280 + q8 * 32 + j * 8) = hold[j];
  }
  __syncthreads();
  // ---- hidden layers + last layer (32x32 MFMA, wave tile = rows rg*32..+31)
  layer_inplace32<16, true>(X, 280, Wh0, e_hb, rg * 32, wc);
  layer_inplace32<16, true>(X, 280, Wh1, e_hb + 256, rg * 32, wc);
  f32x16 acc[2];
  layer_acc32<16>(X, 280, Wl, e_lb, acc, rg * 32, wc);
  // ---- NV-aggregation: rg = batch; rows 0-15 of tile = point pbase,
  //      rows 16-31 = point pbase+1. D rows: (r&3)+8*(r>>2)+4*(lane>>5).
  const int col = lane & 31;
#pragma unroll
  for (int nt = 0; nt < 2; nt++) {
#pragma unroll
    for (int pp = 0; pp < 2; pp++) {
      float s = 0.0f;
#pragma unroll
      for (int r8 = 0; r8 < 8; r8++) s += acc[nt][pp * 8 + r8];
      s += __shfl_xor(s, 32, 64);  // join lane-half row groups -> full 16 rows
      if (lane < 32)
        agg[((rg << 13) + pbase + pp) * 256 + wc * 64 + nt * 32 + col] = (bf16)s;
    }
  }
  // ---- batch-0 edge outputs (rg 0 tile rows = edge rows pbase*16..+31)
  if (rg == 0) {
    const int h = lane >> 5;
#pragma unroll
    for (int nt = 0; nt < 2; nt++)
#pragma unroll
      for (int r = 0; r < 16; r++) {
        const int rr = (r & 3) + 8 * (r >> 2) + 4 * h;
        out_edges[(pbase * 16 + rr) * 256 + wc * 64 + nt * 32 + col] = acc[nt][r];
      }
  }
}

// ---------------- fused node MLP + residual (R3-exact) ----------------------
// 32-row tiles, 512 threads (8 waves: 2 row-groups x 4 col-groups, MT=1).
__global__ __launch_bounds__(512, 4) void node_mlp(
    const float* __restrict__ nodes, const bf16* __restrict__ agg,
    const bf16* __restrict__ Wf, const bf16* __restrict__ Wh0,
    const bf16* __restrict__ Wh1, const bf16* __restrict__ Wl,
    const float* __restrict__ n_fb, const float* __restrict__ n_hb,
    const float* __restrict__ n_lb, float* __restrict__ out_nodes) {
  __shared__ bf16 X[32 * 536];
  const int t = threadIdx.x;
  const int r = t >> 4;   // 32 rows, 16 threads/row
  const int q16 = t & 15;
  const int m = blockIdx.x * 32 + r;
#pragma unroll
  for (int c8 = 0; c8 < 4; c8++) {
    int col = q16 * 8 + c8 * 128;  // 0..511; <256 from nodes, >=256 from agg
    if (col < 256) {
      float4 f0 = *(const float4*)(nodes + m * 256 + col);
      float4 f1 = *(const float4*)(nodes + m * 256 + col + 4);
      bf16x8 v;
      v[0] = (bf16)f0.x; v[1] = (bf16)f0.y; v[2] = (bf16)f0.z; v[3] = (bf16)f0.w;
      v[4] = (bf16)f1.x; v[5] = (bf16)f1.y; v[6] = (bf16)f1.z; v[7] = (bf16)f1.w;
      *(bf16x8*)(X + r * 536 + col) = v;
    } else {
      *(bf16x8*)(X + r * 536 + col) =
          *(const bf16x8*)(agg + m * 256 + (col - 256));
    }
  }
  __syncthreads();
  const int w = t >> 6;
  const int wc = w & 3;
  const int rowOff = (w >> 2) * 16;
  layer_inplace<16, 1, true>(X, 536, 280, Wf, n_fb, rowOff, wc);
  layer_inplace<8, 1, true>(X, 280, 280, Wh0, n_hb, rowOff, wc);
  layer_inplace<8, 1, true>(X, 280, 280, Wh1, n_hb + 256, rowOff, wc);
  f32x4 acc[1][4];
  layer_acc<8, 1>(X, 280, Wl, n_lb, acc, rowOff, wc);
  const int lane = t & 63;
  const int q = lane >> 4;
  const int c = lane & 15;
#pragma unroll
  for (int nt = 0; nt < 4; nt++)
#pragma unroll
    for (int i = 0; i < 4; i++) {
      int mm = blockIdx.x * 32 + rowOff + q * 4 + i;
      int col = wc * 64 + nt * 16 + c;
      out_nodes[mm * 256 + col] = nodes[mm * 256 + col] + acc[0][nt][i];
    }
}

// ---------------- launch ----------------
extern "C" void kernel_launch(void* const* d_in, const int* in_sizes, int n_in,
                              void* d_out, int out_size, void* d_ws,
                              size_t ws_size, hipStream_t stream) {
  const float* nodes = (const float*)d_in[0];
  const float* eattr = (const float*)d_in[1];
  const int* eidx = (const int*)d_in[2];
  const float* e_fw = (const float*)d_in[3];
  const float* e_fb = (const float*)d_in[4];
  const float* e_hw = (const float*)d_in[5];
  const float* e_hb = (const float*)d_in[6];
  const float* e_lw = (const float*)d_in[7];
  const float* e_lb = (const float*)d_in[8];
  const float* n_fw = (const float*)d_in[9];
  const float* n_fb = (const float*)d_in[10];
  const float* n_hw = (const float*)d_in[11];
  const float* n_hb = (const float*)d_in[12];
  const float* n_lw = (const float*)d_in[13];
  const float* n_lb = (const float*)d_in[14];

  // workspace map (bytes); total ~26.6 MB
  char* ws = (char*)d_ws;
  bf16* Sb = (bf16*)(ws + 0);            // [16384][256]
  bf16* Pb = (bf16*)(ws + 8388608);      // [16384][256]
  bf16* aggb = (bf16*)(ws + 16777216);   // [16384][256]
  bf16* wp = (bf16*)(ws + 25165824);     // packed-weight arena, 720896 elems
  bf16* w_self = wp;
  bf16* w_nb = wp + 65536;
  bf16* w_ea = wp + 131072;
  bf16* w_eh0 = wp + 196608;
  bf16* w_eh1 = wp + 262144;
  bf16* w_el = wp + 327680;
  bf16* w_nf = wp + 393216;              // 131072 elems (K=512)
  bf16* w_nh0 = wp + 524288;
  bf16* w_nh1 = wp + 589824;
  bf16* w_nl = wp + 655360;

  float* out_nodes = (float*)d_out;
  float* out_edges = (float*)d_out + 4194304;  // after [B,NP,NL] nodes

  pack_all<<<112, 256, 0, stream>>>(e_fw, e_hw, e_lw, n_fw, n_hw, n_lw, wp);
  producer_sp<<<256, 512, 0, stream>>>(nodes, w_self, w_nb, e_fb, Sb, Pb);
  edge_mlp<<<4096, 512, 0, stream>>>(Sb, Pb, eattr, eidx, w_ea, w_eh0, w_eh1,
                                     w_el, e_hb, e_lb, aggb, out_edges);
  node_mlp<<<512, 512, 0, stream>>>(nodes, aggb, w_nf, w_nh0, w_nh1, w_nl,
                                    n_fb, n_hb, n_lb, out_nodes);
}

// Round 7
// 469.229 us; speedup vs baseline: 1.1857x; 1.0033x over previous
//
#include <hip/hip_runtime.h>
#include <hip/hip_bf16.h>

// GNN processor: NL=256, NP=8192, NV=16, B=2.
// R1: factored first edge layer (S/P/E gather trick) + fused MFMA MLPs. 555us.
// R2: 512-thread/MT=2 blocks (43% occ), merged launches. 481us.
// R3: E-GEMM inlined into edge_mlp (64-row blocks, E computed once). 471us.
// R4/R5: 128-row blocks -> no change (confounded by acc spills: +68MB scratch).
// R6: 32-row blocks, 64% occ -> worse. Occupancy refuted.
// R7: 32x32 MFMA hidden/last (half the MFMA instrs) -> flat 230us. Issue-port
//     refuted. Bank conflicts 11M->4.7M, no effect.
// R8: barrier-phase theory. Block wall ~60k cy vs ~2.5k cy MFMA work; 9-11
//     full-drain barriers/block is the only invariant across R3-R7. Change:
//     LDS ping-pong (Xa/Xb) -> read one buffer, write the other. Kills the
//     pre-overwrite barriers + assembly hold pattern. Edge 9->5 barriers,
//     node 9->4. Everything else R7-exact.
// R9/R10: resubmissions of R8 (infra "container failed twice", no counters).
//     R10 perturbs the source hash (this comment) to dodge any corrupted
//     content-addressed cache entry; code is semantically identical to R8.

typedef __bf16 bf16;
typedef __bf16 bf16x8 __attribute__((ext_vector_type(8)));
typedef float f32x4 __attribute__((ext_vector_type(4)));
typedef float f32x16 __attribute__((ext_vector_type(16)));

#define MFMA16(a, b, c) __builtin_amdgcn_mfma_f32_16x16x32_bf16((a), (b), (c), 0, 0, 0)
#define MFMA32(a, b, c) __builtin_amdgcn_mfma_f32_32x32x16_bf16((a), (b), (c), 0, 0, 0)

constexpr int kNP = 8192;
constexpr int kNV = 16;

// ---------------- weight packing (112 blocks, coalesced reads) --------------
// 16x16 layout (producer/node/E): dst[((nt*kd+ks)*64+lane)*8+j]
//   = W[ks*32+(lane>>4)*8+j][nt*16+(lane&15)]
// 32x32 layout (edge hidden/last): dst[((wcnt*16+ks)*64+lane)*8+j]
//   = W[ks*16+(lane>>5)*8+j][wcnt*32+(lane&31)]
__global__ __launch_bounds__(256) void pack_all(
    const float* __restrict__ e_fw, const float* __restrict__ e_hw,
    const float* __restrict__ e_lw, const float* __restrict__ n_fw,
    const float* __restrict__ n_hw, const float* __restrict__ n_lw,
    bf16* __restrict__ wp) {
  const int s = blockIdx.x;  // 0..111
  const int t = threadIdx.x;
  const int lane = t & 63;
  const int w = t >> 6;
  if (s < 64) {  // ---- 16x16 fragment packing
    const float* src;
    bf16* dst;
    int ks, kd = 8;
    if (s < 24)      { src = e_fw + (s >> 3) * 65536; dst = wp + (s >> 3) * 65536; ks = s & 7; }
    else if (s < 40) { src = n_fw;          dst = wp + 393216; ks = s - 24; kd = 16; }
    else if (s < 48) { src = n_hw;          dst = wp + 524288; ks = s - 40; }
    else if (s < 56) { src = n_hw + 65536;  dst = wp + 589824; ks = s - 48; }
    else             { src = n_lw;          dst = wp + 655360; ks = s - 56; }
    const int q = lane >> 4;
    const int c = lane & 15;
#pragma unroll
    for (int nti = 0; nti < 4; nti++) {
      const int nt = w * 4 + nti;
      bf16x8 v;
#pragma unroll
      for (int j = 0; j < 8; j++)
        v[j] = (bf16)src[(ks * 32 + q * 8 + j) * 256 + nt * 16 + c];
      *(bf16x8*)(dst + (((nt * kd + ks) * 64 + lane) << 3)) = v;
    }
  } else {  // ---- 32x32 fragment packing: e_hw0 / e_hw1 / e_lw
    const int s2 = s - 64;
    const int mat = s2 >> 4;    // 0..2
    const int ks = s2 & 15;     // 0..15
    const float* src = (mat == 0) ? e_hw : (mat == 1) ? (e_hw + 65536) : e_lw;
    bf16* dst = wp + 196608 + mat * 65536;
    const int ko = lane >> 5;
    const int col = lane & 31;
#pragma unroll
    for (int h = 0; h < 2; h++) {
      const int wcnt = w * 2 + h;  // 0..7
      bf16x8 v;
#pragma unroll
      for (int j = 0; j < 8; j++)
        v[j] = (bf16)src[(ks * 16 + ko * 8 + j) * 256 + wcnt * 32 + col];
      *(bf16x8*)(dst + (((wcnt * 16 + ks) * 64 + lane) << 3)) = v;
    }
  }
}

// ---------------- 16x16 MFMA layer primitives (producer/node/E) -------------
// C/D: col = lane&15, row = (lane>>4)*4 + i
template <int KD, int MT>
__device__ __forceinline__ void layer_acc(const bf16* X, int xs,
                                          const bf16* __restrict__ Wp,
                                          const float* __restrict__ bias,
                                          f32x4 (&acc)[MT][4], int rowOff,
                                          int wc) {
  const int lane = threadIdx.x & 63;
  const int q = lane >> 4;
  const int c = lane & 15;
#pragma unroll
  for (int nt = 0; nt < 4; nt++) {
    float bv = bias ? bias[wc * 64 + nt * 16 + c] : 0.0f;
#pragma unroll
    for (int mt = 0; mt < MT; mt++) {
      acc[mt][nt][0] = bv; acc[mt][nt][1] = bv;
      acc[mt][nt][2] = bv; acc[mt][nt][3] = bv;
    }
  }
#pragma unroll
  for (int ks = 0; ks < KD; ks++) {
    bf16x8 a[MT];
#pragma unroll
    for (int mt = 0; mt < MT; mt++)
      a[mt] = *(const bf16x8*)(X + (rowOff + mt * 16 + c) * xs + ks * 32 + q * 8);
    bf16x8 bb[4];
#pragma unroll
    for (int nt = 0; nt < 4; nt++)
      bb[nt] = *(const bf16x8*)(Wp + ((((wc * 4 + nt) * KD + ks) * 64 + lane) << 3));
#pragma unroll
    for (int mt = 0; mt < MT; mt++)
#pragma unroll
      for (int nt = 0; nt < 4; nt++)
        acc[mt][nt] = MFMA16(a[mt], bb[nt], acc[mt][nt]);
  }
}

// ping-pong layer: read Xr (stride xs_r), write Yw (stride xs_w). NO internal
// barriers — caller places ONE __syncthreads() after.
template <int KD, int MT, bool RELU>
__device__ __forceinline__ void layer_pp(const bf16* Xr, int xs_r, bf16* Yw,
                                         int xs_w, const bf16* __restrict__ Wp,
                                         const float* __restrict__ bias,
                                         int rowOff, int wc) {
  f32x4 acc[MT][4];
  layer_acc<KD, MT>(Xr, xs_r, Wp, bias, acc, rowOff, wc);
  const int lane = threadIdx.x & 63;
  const int q = lane >> 4;
  const int c = lane & 15;
#pragma unroll
  for (int mt = 0; mt < MT; mt++)
#pragma unroll
    for (int nt = 0; nt < 4; nt++)
#pragma unroll
      for (int i = 0; i < 4; i++) {
        float v = acc[mt][nt][i];
        if (RELU) v = fmaxf(v, 0.0f);
        Yw[(rowOff + mt * 16 + q * 4 + i) * xs_w + (wc * 64 + nt * 16 + c)] = (bf16)v;
      }
}

// ---------------- 32x32 MFMA layer primitives (edge hidden/last) ------------
// Wave tile: 32 rows x 64 cols (2 nt' of 32 cols), K via KD2 steps of 16.
// C/D: col = lane&31, row = (r&3) + 8*(r>>2) + 4*(lane>>5), r in [0,16)
template <int KD2>
__device__ __forceinline__ void layer_acc32(const bf16* X, int xs,
                                            const bf16* __restrict__ Wp,
                                            const float* __restrict__ bias,
                                            f32x16 (&acc)[2], int rowOff,
                                            int wc) {
  const int lane = threadIdx.x & 63;
  const int row = lane & 31;
  const int ko = lane >> 5;
  const int col = lane & 31;
#pragma unroll
  for (int nt = 0; nt < 2; nt++) {
    float bv = bias ? bias[wc * 64 + nt * 32 + col] : 0.0f;
#pragma unroll
    for (int r = 0; r < 16; r++) acc[nt][r] = bv;
  }
#pragma unroll
  for (int ks = 0; ks < KD2; ks++) {
    bf16x8 a = *(const bf16x8*)(X + (rowOff + row) * xs + ks * 16 + ko * 8);
#pragma unroll
    for (int nt = 0; nt < 2; nt++) {
      bf16x8 b = *(const bf16x8*)(Wp + ((((wc * 2 + nt) * KD2 + ks) * 64 + lane) << 3));
      acc[nt] = MFMA32(a, b, acc[nt]);
    }
  }
}

template <int KD2, bool RELU>
__device__ __forceinline__ void layer_pp32(const bf16* Xr, int xs, bf16* Yw,
                                           const bf16* __restrict__ Wp,
                                           const float* __restrict__ bias,
                                           int rowOff, int wc) {
  f32x16 acc[2];
  layer_acc32<KD2>(Xr, xs, Wp, bias, acc, rowOff, wc);
  const int lane = threadIdx.x & 63;
  const int h = lane >> 5;
  const int col = lane & 31;
#pragma unroll
  for (int nt = 0; nt < 2; nt++)
#pragma unroll
    for (int r = 0; r < 16; r++) {
      float v = acc[nt][r];
      if (RELU) v = fmaxf(v, 0.0f);
      const int rr = (r & 3) + 8 * (r >> 2) + 4 * h;
      Yw[(rowOff + rr) * xs + (wc * 64 + nt * 32 + col)] = (bf16)v;
    }
}

// ---------------- S+P producer: one staged tile, two GEMMs (R3-exact) -------
// 256 blocks x 64 rows: S = nodes@Wa + e_fb ; P = nodes@Wb. Direct acc->global.
__global__ __launch_bounds__(512, 4) void producer_sp(
    const float* __restrict__ nodes, const bf16* __restrict__ w_self,
    const bf16* __restrict__ w_nb, const float* __restrict__ e_fb,
    bf16* __restrict__ Sb, bf16* __restrict__ Pb) {
  __shared__ bf16 X[64 * 280];
  const int t = threadIdx.x;
  const int m0 = blockIdx.x * 64;
  {
    const int r = t >> 3;   // 64 rows, 8 threads/row
    const int q8 = t & 7;
#pragma unroll
    for (int c8 = 0; c8 < 4; c8++) {
      int col = q8 * 8 + c8 * 64;
      float4 f0 = *(const float4*)(nodes + (m0 + r) * 256 + col);
      float4 f1 = *(const float4*)(nodes + (m0 + r) * 256 + col + 4);
      bf16x8 v;
      v[0] = (bf16)f0.x; v[1] = (bf16)f0.y; v[2] = (bf16)f0.z; v[3] = (bf16)f0.w;
      v[4] = (bf16)f1.x; v[5] = (bf16)f1.y; v[6] = (bf16)f1.z; v[7] = (bf16)f1.w;
      *(bf16x8*)(X + r * 280 + col) = v;
    }
  }
  __syncthreads();
  const int lane = t & 63;
  const int w = t >> 6;
  const int wc = w & 3;
  const int rowOff = (w >> 2) * 32;
  const int q = lane >> 4;
  const int c = lane & 15;
  f32x4 acc[2][4];
  layer_acc<8, 2>(X, 280, w_self, e_fb, acc, rowOff, wc);
#pragma unroll
  for (int mt = 0; mt < 2; mt++)
#pragma unroll
    for (int nt = 0; nt < 4; nt++)
#pragma unroll
      for (int i = 0; i < 4; i++)
        Sb[(m0 + rowOff + mt * 16 + q * 4 + i) * 256 + wc * 64 + nt * 16 + c] =
            (bf16)acc[mt][nt][i];
  layer_acc<8, 2>(X, 280, w_nb, nullptr, acc, rowOff, wc);
#pragma unroll
  for (int mt = 0; mt < 2; mt++)
#pragma unroll
    for (int nt = 0; nt < 4; nt++)
#pragma unroll
      for (int i = 0; i < 4; i++)
        Pb[(m0 + rowOff + mt * 16 + q * 4 + i) * 256 + wc * 64 + nt * 16 + c] =
            (bf16)acc[mt][nt][i];
}

// ---------------- fused edge MLP: ping-pong LDS, 5 barriers -----------------
// Block = 2 points x 16 v x 2 batches = 64 rows. E computed once (16x16 path),
// hidden/last 32x32. Xa/Xb ping-pong: stage->Xa[32..63], E->Xb[32..63],
// assemble->Xa[0..63], h0->Xb, h1->Xa, last reads Xa.
__global__ __launch_bounds__(512, 4) void edge_mlp(
    const bf16* __restrict__ S, const bf16* __restrict__ P,
    const float* __restrict__ eattr, const int* __restrict__ idx,
    const bf16* __restrict__ w_ea, const bf16* __restrict__ Wh0,
    const bf16* __restrict__ Wh1, const bf16* __restrict__ Wl,
    const float* __restrict__ e_hb, const float* __restrict__ e_lb,
    bf16* __restrict__ agg, float* __restrict__ out_edges) {
  __shared__ bf16 L[2 * 64 * 280];
  bf16* Xa = L;
  bf16* Xb = L + 64 * 280;
  const int t = threadIdx.x;
  const int pbase = blockIdx.x * 2;  // 4096 blocks
  // ---- stage eattr (32 rows fp32) into Xa rows 32..63 as bf16
  {
    const int r = t >> 4;     // 0..31
    const int q16 = t & 15;   // 16 cols each
    const float* src = eattr + (pbase * 16 + r) * 256 + q16 * 16;
    bf16* dst = Xa + (32 + r) * 280 + q16 * 16;
    float4 f0 = *(const float4*)(src);
    float4 f1 = *(const float4*)(src + 4);
    float4 f2 = *(const float4*)(src + 8);
    float4 f3 = *(const float4*)(src + 12);
    bf16x8 v0, v1;
    v0[0] = (bf16)f0.x; v0[1] = (bf16)f0.y; v0[2] = (bf16)f0.z; v0[3] = (bf16)f0.w;
    v0[4] = (bf16)f1.x; v0[5] = (bf16)f1.y; v0[6] = (bf16)f1.z; v0[7] = (bf16)f1.w;
    v1[0] = (bf16)f2.x; v1[1] = (bf16)f2.y; v1[2] = (bf16)f2.z; v1[3] = (bf16)f2.w;
    v1[4] = (bf16)f3.x; v1[5] = (bf16)f3.y; v1[6] = (bf16)f3.z; v1[7] = (bf16)f3.w;
    *(bf16x8*)(dst) = v0;
    *(bf16x8*)(dst + 8) = v1;
  }
  __syncthreads();  // [1]
  const int lane = t & 63;
  const int w = t >> 6;
  const int wc = w & 3;
  const int rg = w >> 2;
  const int q = lane >> 4;
  const int c = lane & 15;
  // ---- E-GEMM (16x16): read Xa[32..63], write Xb[32..63]
  {
    f32x4 acce[1][4];
    layer_acc<8, 1>(Xa, 280, w_ea, nullptr, acce, 32 + rg * 16, wc);
#pragma unroll
    for (int nt = 0; nt < 4; nt++)
#pragma unroll
      for (int i = 0; i < 4; i++)
        Xb[(32 + rg * 16 + q * 4 + i) * 280 + wc * 64 + nt * 16 + c] =
            (bf16)acce[0][nt][i];
  }
  __syncthreads();  // [2]
  // ---- assemble relu(S + Pgather + E): read Xb[32..63], write Xa[0..63]
  {
    const int r = t >> 3;     // 0..63
    const int q8 = t & 7;     // 32 cols each
    const int b = r >> 5;
    const int rr = r & 31;
    const int p = pbase + (rr >> 4);
    const int v = rr & 15;
    const int nb = idx[p * kNV + v];
    const bf16* Srow = S + ((b << 13) + p) * 256;
    const bf16* Prow = P + ((b << 13) + nb) * 256;
#pragma unroll
    for (int j = 0; j < 4; j++) {
      int col = q8 * 32 + j * 8;
      bf16x8 ev = *(const bf16x8*)(Xb + (32 + rr) * 280 + col);
      bf16x8 sv = *(const bf16x8*)(Srow + col);
      bf16x8 pv = *(const bf16x8*)(Prow + col);
      bf16x8 o;
#pragma unroll
      for (int k = 0; k < 8; k++) {
        float f = (float)sv[k] + (float)pv[k] + (float)ev[k];
        o[k] = (bf16)fmaxf(f, 0.0f);
      }
      *(bf16x8*)(Xa + r * 280 + col) = o;
    }
  }
  __syncthreads();  // [3]
  // ---- hidden + last (32x32): Xa->Xb, Xb->Xa, read Xa
  layer_pp32<16, true>(Xa, 280, Xb, Wh0, e_hb, rg * 32, wc);
  __syncthreads();  // [4]
  layer_pp32<16, true>(Xb, 280, Xa, Wh1, e_hb + 256, rg * 32, wc);
  __syncthreads();  // [5]
  f32x16 acc[2];
  layer_acc32<16>(Xa, 280, Wl, e_lb, acc, rg * 32, wc);
  // ---- NV-aggregation: rg = batch; tile rows 16pp.. = point pbase+pp
  const int col = lane & 31;
#pragma unroll
  for (int nt = 0; nt < 2; nt++) {
#pragma unroll
    for (int pp = 0; pp < 2; pp++) {
      float s = 0.0f;
#pragma unroll
      for (int r8 = 0; r8 < 8; r8++) s += acc[nt][pp * 8 + r8];
      s += __shfl_xor(s, 32, 64);  // join lane-half row groups -> full 16 rows
      if (lane < 32)
        agg[((rg << 13) + pbase + pp) * 256 + wc * 64 + nt * 32 + col] = (bf16)s;
    }
  }
  // ---- batch-0 edge outputs (rg 0 tile rows = edge rows pbase*16..+31)
  if (rg == 0) {
    const int h = lane >> 5;
#pragma unroll
    for (int nt = 0; nt < 2; nt++)
#pragma unroll
      for (int r = 0; r < 16; r++) {
        const int rr = (r & 3) + 8 * (r >> 2) + 4 * h;
        out_edges[(pbase * 16 + rr) * 256 + wc * 64 + nt * 32 + col] = acc[nt][r];
      }
  }
}

// ---------------- fused node MLP + residual: ping-pong LDS, 4 barriers ------
// 32-row tiles, 512 threads (8 waves: 2 row-groups x 4 col-groups, MT=1).
// Xa [32][536] (stage), Xb [32][280]. f: Xa->Xb, h0: Xb->Xa, h1: Xa->Xb,
// last reads Xb.
__global__ __launch_bounds__(512, 4) void node_mlp(
    const float* __restrict__ nodes, const bf16* __restrict__ agg,
    const bf16* __restrict__ Wf, const bf16* __restrict__ Wh0,
    const bf16* __restrict__ Wh1, const bf16* __restrict__ Wl,
    const float* __restrict__ n_fb, const float* __restrict__ n_hb,
    const float* __restrict__ n_lb, float* __restrict__ out_nodes) {
  __shared__ bf16 L[32 * 536 + 32 * 280];
  bf16* Xa = L;             // stride 536
  bf16* Xb = L + 32 * 536;  // stride 280
  const int t = threadIdx.x;
  const int r = t >> 4;   // 32 rows, 16 threads/row
  const int q16 = t & 15;
  const int m = blockIdx.x * 32 + r;
#pragma unroll
  for (int c8 = 0; c8 < 4; c8++) {
    int col = q16 * 8 + c8 * 128;  // 0..511; <256 from nodes, >=256 from agg
    if (col < 256) {
      float4 f0 = *(const float4*)(nodes + m * 256 + col);
      float4 f1 = *(const float4*)(nodes + m * 256 + col + 4);
      bf16x8 v;
      v[0] = (bf16)f0.x; v[1] = (bf16)f0.y; v[2] = (bf16)f0.z; v[3] = (bf16)f0.w;
      v[4] = (bf16)f1.x; v[5] = (bf16)f1.y; v[6] = (bf16)f1.z; v[7] = (bf16)f1.w;
      *(bf16x8*)(Xa + r * 536 + col) = v;
    } else {
      *(bf16x8*)(Xa + r * 536 + col) =
          *(const bf16x8*)(agg + m * 256 + (col - 256));
    }
  }
  __syncthreads();  // [1]
  const int w = t >> 6;
  const int wc = w & 3;
  const int rowOff = (w >> 2) * 16;
  layer_pp<16, 1, true>(Xa, 536, Xb, 280, Wf, n_fb, rowOff, wc);
  __syncthreads();  // [2]
  layer_pp<8, 1, true>(Xb, 280, Xa, 536, Wh0, n_hb, rowOff, wc);
  __syncthreads();  // [3]
  layer_pp<8, 1, true>(Xa, 536, Xb, 280, Wh1, n_hb + 256, rowOff, wc);
  __syncthreads();  // [4]
  f32x4 acc[1][4];
  layer_acc<8, 1>(Xb, 280, Wl, n_lb, acc, rowOff, wc);
  const int lane = t & 63;
  const int q = lane >> 4;
  const int c = lane & 15;
#pragma unroll
  for (int nt = 0; nt < 4; nt++)
#pragma unroll
    for (int i = 0; i < 4; i++) {
      int mm = blockIdx.x * 32 + rowOff + q * 4 + i;
      int col = wc * 64 + nt * 16 + c;
      out_nodes[mm * 256 + col] = nodes[mm * 256 + col] + acc[0][nt][i];
    }
}

// ---------------- launch ----------------
extern "C" void kernel_launch(void* const* d_in, const int* in_sizes, int n_in,
                              void* d_out, int out_size, void* d_ws,
                              size_t ws_size, hipStream_t stream) {
  const float* nodes = (const float*)d_in[0];
  const float* eattr = (const float*)d_in[1];
  const int* eidx = (const int*)d_in[2];
  const float* e_fw = (const float*)d_in[3];
  const float* e_fb = (const float*)d_in[4];
  const float* e_hw = (const float*)d_in[5];
  const float* e_hb = (const float*)d_in[6];
  const float* e_lw = (const float*)d_in[7];
  const float* e_lb = (const float*)d_in[8];
  const float* n_fw = (const float*)d_in[9];
  const float* n_fb = (const float*)d_in[10];
  const float* n_hw = (const float*)d_in[11];
  const float* n_hb = (const float*)d_in[12];
  const float* n_lw = (const float*)d_in[13];
  const float* n_lb = (const float*)d_in[14];

  // workspace map (bytes); total ~26.6 MB
  char* ws = (char*)d_ws;
  bf16* Sb = (bf16*)(ws + 0);            // [16384][256]
  bf16* Pb = (bf16*)(ws + 8388608);      // [16384][256]
  bf16* aggb = (bf16*)(ws + 16777216);   // [16384][256]
  bf16* wp = (bf16*)(ws + 25165824);     // packed-weight arena, 720896 elems
  bf16* w_self = wp;
  bf16* w_nb = wp + 65536;
  bf16* w_ea = wp + 131072;
  bf16* w_eh0 = wp + 196608;
  bf16* w_eh1 = wp + 262144;
  bf16* w_el = wp + 327680;
  bf16* w_nf = wp + 393216;              // 131072 elems (K=512)
  bf16* w_nh0 = wp + 524288;
  bf16* w_nh1 = wp + 589824;
  bf16* w_nl = wp + 655360;

  float* out_nodes = (float*)d_out;
  float* out_edges = (float*)d_out + 4194304;  // after [B,NP,NL] nodes

  pack_all<<<112, 256, 0, stream>>>(e_fw, e_hw, e_lw, n_fw, n_hw, n_lw, wp);
  producer_sp<<<256, 512, 0, stream>>>(nodes, w_self, w_nb, e_fb, Sb, Pb);
  edge_mlp<<<4096, 512, 0, stream>>>(Sb, Pb, eattr, eidx, w_ea, w_eh0, w_eh1,
                                     w_el, e_hb, e_lb, aggb, out_edges);
  node_mlp<<<512, 512, 0, stream>>>(nodes, aggb, w_nf, w_nh0, w_nh1, w_nl,
                                    n_fb, n_hb, n_lb, out_nodes);
}